// Round 2
// baseline (815.054 us; speedup 1.0000x reference)
//
#include <hip/hip_runtime.h>
#include <hip/hip_bf16.h>

#define NEG_SLOPE 0.2f
#define KS 32

// ---------------------------------------------------------------------------
// W transpose: W[h][k][f] (4,256,64) -> Wc[k][h*64+f] (256,256)
// ---------------------------------------------------------------------------
__global__ __launch_bounds__(256) void wtrans_k(const float* __restrict__ W,
                                                float* __restrict__ Wc)
{
    int tid = blockIdx.x * 256 + threadIdx.x;   // 0..65535
    int k = tid >> 8, c = tid & 255;
    int h = c >> 6, f = c & 63;
    Wc[tid] = W[h * 16384 + k * 64 + f];
}

// ---------------------------------------------------------------------------
// Fused GEMM: HP[n][256] = X[n][256] @ Wc[256][256]
// + fused attention projections: as_[n][4], at_[n][4] via atomicAdd
// Tile 64x128, 256 threads, micro 4x8 (two float4 col-frags at +0,+32).
// A staged TRANSPOSED in LDS -> 1x b128 A-read + 2x b128 B-read per kk.
// ---------------------------------------------------------------------------
__global__ __launch_bounds__(256) void gemm_fused_k(
    const float* __restrict__ X,      // [n,256]
    const float* __restrict__ Wc,     // [256,256]
    const float* __restrict__ a_src,  // [4,64]
    const float* __restrict__ a_trg,  // [4,64]
    float* __restrict__ HP,           // [n,256]
    float* __restrict__ as_,          // [n,4] (zeroed)
    float* __restrict__ at_,          // [n,4] (zeroed)
    int n)
{
    const int row0 = blockIdx.x * 64;
    const int col0 = blockIdx.y * 128;
    __shared__ float Ast[KS][68];     // transposed: Ast[k][row], stride 68 (16B-aligned)
    __shared__ float Bs[KS][132];     // Bs[k][col], stride 132 (16B-aligned)

    const int t  = threadIdx.x;
    const int w  = t >> 6;            // wave 0..3
    const int lr = t & 63;
    const int a  = lr >> 3;           // 0..7 row group
    const int b  = lr & 7;            // 0..7 col group
    const int rbase = (w >> 1) * 32 + a * 4;          // block-local rows rbase..+3
    const int cbase = (w & 1) * 64 + b * 4;           // frags at cbase, cbase+32

    float acc[4][8] = {};

    for (int k0 = 0; k0 < 256; k0 += KS) {
        __syncthreads();
        // stage A: 64 rows x 32 k, written transposed
        #pragma unroll
        for (int i = 0; i < 2; ++i) {
            int lin = t + i * 256;        // 0..511
            int r   = lin >> 3;           // 0..63
            int c4  = lin & 7;            // 0..7
            int gr  = row0 + r;
            float4 v = make_float4(0.f, 0.f, 0.f, 0.f);
            if (gr < n) v = *(const float4*)(X + (size_t)gr * 256 + k0 + c4 * 4);
            Ast[c4 * 4 + 0][r] = v.x; Ast[c4 * 4 + 1][r] = v.y;
            Ast[c4 * 4 + 2][r] = v.z; Ast[c4 * 4 + 3][r] = v.w;
        }
        // stage B: 32 k x 128 cols
        #pragma unroll
        for (int i = 0; i < 4; ++i) {
            int lin = t + i * 256;        // 0..1023
            int kr  = lin >> 5;           // 0..31
            int c4  = lin & 31;           // 0..31
            float4 v = *(const float4*)(Wc + (size_t)(k0 + kr) * 256 + col0 + c4 * 4);
            *(float4*)&Bs[kr][c4 * 4] = v;
        }
        __syncthreads();

        #pragma unroll
        for (int kk = 0; kk < KS; ++kk) {
            float av[4], bv[8];
            *(float4*)av      = *(const float4*)&Ast[kk][rbase];
            *(float4*)&bv[0]  = *(const float4*)&Bs[kk][cbase];
            *(float4*)&bv[4]  = *(const float4*)&Bs[kk][cbase + 32];
            #pragma unroll
            for (int i = 0; i < 4; ++i)
                #pragma unroll
                for (int j = 0; j < 8; ++j)
                    acc[i][j] += av[i] * bv[j];
        }
    }

    // epilogue: store HP + fused projections
    const int h  = blockIdx.y * 2 + (w & 1);
    const int fb = b * 4;              // within-head offset of first frag
    float pa[8], pt[8];
    #pragma unroll
    for (int j = 0; j < 4; ++j) {
        pa[j]     = a_src[h * 64 + fb + j];
        pa[4 + j] = a_src[h * 64 + 32 + fb + j];
        pt[j]     = a_trg[h * 64 + fb + j];
        pt[4 + j] = a_trg[h * 64 + 32 + fb + j];
    }
    #pragma unroll
    for (int i = 0; i < 4; ++i) {
        int gr = row0 + rbase + i;
        if (gr < n) {
            *(float4*)(HP + (size_t)gr * 256 + col0 + cbase)      = *(float4*)&acc[i][0];
            *(float4*)(HP + (size_t)gr * 256 + col0 + cbase + 32) = *(float4*)&acc[i][4];
            float ps = 0.f, pv = 0.f;
            #pragma unroll
            for (int j = 0; j < 8; ++j) { ps += acc[i][j] * pa[j]; pv += acc[i][j] * pt[j]; }
            atomicAdd(&as_[gr * 4 + h], ps);
            atomicAdd(&at_[gr * 4 + h], pv);
        }
    }
}

// ---------------------------------------------------------------------------
// CSR build: histogram -> scan -> scatter src values sorted by trg
// ---------------------------------------------------------------------------
__global__ void hist_k(const int* __restrict__ trg, int* __restrict__ counts,
                       int* __restrict__ ranks, int E)
{
    int e = blockIdx.x * blockDim.x + threadIdx.x;
    if (e < E) ranks[e] = atomicAdd(&counts[trg[e]], 1);
}

__global__ __launch_bounds__(1024) void scan_k(const int* __restrict__ counts,
                                               int* __restrict__ starts, int n)
{
    const int T = 1024;
    int t = threadIdx.x;
    int chunk = (n + T - 1) / T;
    int beg = t * chunk;
    int end = min(beg + chunk, n);
    int sum = 0;
    for (int i = beg; i < end; ++i) sum += counts[i];
    __shared__ int lds[T];
    lds[t] = sum;
    __syncthreads();
    for (int off = 1; off < T; off <<= 1) {
        int v = (t >= off) ? lds[t - off] : 0;
        __syncthreads();
        lds[t] += v;
        __syncthreads();
    }
    int run = lds[t] - sum;
    for (int i = beg; i < end; ++i) { starts[i] = run; run += counts[i]; }
    if (t == T - 1) starts[n] = lds[T - 1];
}

__global__ void scatter_k(const int* __restrict__ src, const int* __restrict__ trg,
                          const int* __restrict__ starts, const int* __restrict__ ranks,
                          int* __restrict__ srcs, int E)
{
    int e = blockIdx.x * blockDim.x + threadIdx.x;
    if (e < E) srcs[starts[trg[e]] + ranks[e]] = src[e];
}

// ---------------------------------------------------------------------------
// Aggregation, one WAVE per node. hp layout [n][256] (h*64+f fused).
// lane l: head h=l>>4, cols 4l..4l+3. Per edge: one coalesced 1KB row read.
// out = (sum_e p_e * hp[src_e]) / (sum_e p_e + 1e-16)
// LAYER 0: elu -> buf[n][256].  LAYER 1: head-mean -> out[n][64].
// ---------------------------------------------------------------------------
template<int LAYER>
__global__ __launch_bounds__(256) void aggregate_k(
    const float* __restrict__ HP, const float* __restrict__ as_,
    const float* __restrict__ at_, const int* __restrict__ starts,
    const int* __restrict__ srcs, float* __restrict__ out, int n)
{
    const int w = threadIdx.x >> 6;
    const int l = threadIdx.x & 63;
    const int v = blockIdx.x * 4 + w;
    if (v >= n) return;
    const int h = l >> 4;
    const int s0 = starts[v];
    const int s1 = starts[v + 1];
    const float atv = at_[v * 4 + h];

    float4 acc = make_float4(0.f, 0.f, 0.f, 0.f);
    float den = 0.f;

    for (int base = s0; base < s1; base += 64) {
        int m = min(64, s1 - base);
        int s_l = (base + l < s1) ? srcs[base + l] : 0;
        #pragma unroll 2
        for (int i = 0; i < m; ++i) {
            int s = __shfl(s_l, i, 64);
            float e = as_[s * 4 + h] + atv;
            e = (e > 0.f) ? e : NEG_SLOPE * e;
            float p = expf(e);
            den += p;
            float4 hv = *(const float4*)(HP + (size_t)s * 256 + l * 4);
            acc.x += p * hv.x; acc.y += p * hv.y;
            acc.z += p * hv.z; acc.w += p * hv.w;
        }
    }

    float r = 1.f / (den + 1e-16f);
    acc.x *= r; acc.y *= r; acc.z *= r; acc.w *= r;

    if (LAYER == 0) {
        acc.x = (acc.x > 0.f) ? acc.x : expm1f(acc.x);
        acc.y = (acc.y > 0.f) ? acc.y : expm1f(acc.y);
        acc.z = (acc.z > 0.f) ? acc.z : expm1f(acc.z);
        acc.w = (acc.w > 0.f) ? acc.w : expm1f(acc.w);
        *(float4*)(out + (size_t)v * 256 + l * 4) = acc;
    } else {
        // head mean: lanes l, l^16, l^32, l^48 hold same f-slot, different h
        acc.x += __shfl_xor(acc.x, 16, 64); acc.y += __shfl_xor(acc.y, 16, 64);
        acc.z += __shfl_xor(acc.z, 16, 64); acc.w += __shfl_xor(acc.w, 16, 64);
        acc.x += __shfl_xor(acc.x, 32, 64); acc.y += __shfl_xor(acc.y, 32, 64);
        acc.z += __shfl_xor(acc.z, 32, 64); acc.w += __shfl_xor(acc.w, 32, 64);
        if (l < 16) {
            acc.x *= 0.25f; acc.y *= 0.25f; acc.z *= 0.25f; acc.w *= 0.25f;
            *(float4*)(out + (size_t)v * 64 + l * 4) = acc;
        }
    }
}

// ---------------------------------------------------------------------------
// final: logits = [out_u | out_t] @ fc_w + fc_b ; log_softmax over 16
// ---------------------------------------------------------------------------
__global__ __launch_bounds__(256) void final_k(
    const float* __restrict__ out_u, const float* __restrict__ out_t,
    const float* __restrict__ fcw, const float* __restrict__ fcb,
    float* __restrict__ out, int nret)
{
    int gid = blockIdx.x * blockDim.x + threadIdx.x;
    int nn = gid >> 4;
    int j  = gid & 15;
    if (nn >= nret) return;
    const float* ru = out_u + (size_t)nn * 64;
    const float* rt = out_t + (size_t)nn * 64;
    float acc = fcb[j];
    #pragma unroll 8
    for (int k = 0; k < 64; ++k) acc += ru[k] * fcw[k * 16 + j];
    #pragma unroll 8
    for (int k = 0; k < 64; ++k) acc += rt[k] * fcw[(64 + k) * 16 + j];

    float m = acc;
    for (int off = 8; off; off >>= 1) m = fmaxf(m, __shfl_xor(m, off, 16));
    float ex = expf(acc - m);
    float s = ex;
    for (int off = 8; off; off >>= 1) s += __shfl_xor(s, off, 16);
    out[(size_t)nn * 16 + j] = acc - m - logf(s);
}

// ---------------------------------------------------------------------------
extern "C" void kernel_launch(void* const* d_in, const int* in_sizes, int n_in,
                              void* d_out, int out_size, void* d_ws, size_t ws_size,
                              hipStream_t stream)
{
    const int N = in_sizes[0] / 256;     // 20000
    const int E = in_sizes[2];           // 320000
    const int NRET = out_size / 16;      // 20000

    const float* emb[2] = { (const float*)d_in[0], (const float*)d_in[1] };
    const int*   srcI[2] = { (const int*)d_in[2], (const int*)d_in[4] };
    const int*   trgI[2] = { (const int*)d_in[3], (const int*)d_in[5] };
    const float* fcw = (const float*)d_in[18];
    const float* fcb = (const float*)d_in[19];

    // workspace layout (floats unless noted)
    float* hp    = (float*)d_ws;                      // N*256
    float* buf   = hp + (size_t)N * 256;              // N*256
    float* as_   = buf + (size_t)N * 256;             // N*4
    float* at_   = as_ + (size_t)N * 4;               // N*4  (adjacent for one memset)
    float* out_s[2];
    out_s[0] = at_ + (size_t)N * 4;                   // N*64
    out_s[1] = out_s[0] + (size_t)N * 64;             // N*64
    float* wcat  = out_s[1] + (size_t)N * 64;         // 65536
    int* starts  = (int*)(wcat + 65536);              // N+1
    int* counts  = starts + (N + 1);                  // N
    int* ranks   = counts + N;                        // E
    int* srcs    = ranks + E;                         // E

    const int EB = (E + 255) / 256;
    const dim3 gemm_grid((N + 63) / 64, 2);
    const int agg_grid = (N + 3) / 4;

    for (int side = 0; side < 2; ++side) {
        // CSR build (shared by both layers of this side)
        hipMemsetAsync(counts, 0, (size_t)N * sizeof(int), stream);
        hist_k<<<EB, 256, 0, stream>>>(trgI[side], counts, ranks, E);
        scan_k<<<1, 1024, 0, stream>>>(counts, starts, N);
        scatter_k<<<EB, 256, 0, stream>>>(srcI[side], trgI[side], starts, ranks, srcs, E);

        for (int layer = 0; layer < 2; ++layer) {
            const float* wl  = (const float*)d_in[6 + side * 6 + layer * 3 + 0];
            const float* asl = (const float*)d_in[6 + side * 6 + layer * 3 + 1];
            const float* atl = (const float*)d_in[6 + side * 6 + layer * 3 + 2];
            const float* x   = (layer == 0) ? emb[side] : buf;

            hipMemsetAsync(as_, 0, (size_t)N * 8 * sizeof(float), stream);
            wtrans_k<<<256, 256, 0, stream>>>(wl, wcat);
            gemm_fused_k<<<gemm_grid, 256, 0, stream>>>(x, wcat, asl, atl,
                                                        hp, as_, at_, N);
            if (layer == 0)
                aggregate_k<0><<<agg_grid, 256, 0, stream>>>(hp, as_, at_, starts,
                                                             srcs, buf, N);
            else
                aggregate_k<1><<<agg_grid, 256, 0, stream>>>(hp, as_, at_, starts,
                                                             srcs, out_s[side], N);
        }
    }

    final_k<<<(NRET * 16 + 255) / 256, 256, 0, stream>>>(out_s[0], out_s[1], fcw, fcb,
                                                         (float*)d_out, NRET);
}